// Round 5
// baseline (533.766 us; speedup 1.0000x reference)
//
#include <hip/hip_runtime.h>
#include <math.h>

#define H 2048
#define NV 32
#define DK 128
#define DV 128
#define KEY_DIM 2048
#define VALUE_DIM 4096
#define CONV_DIM 8192               // 2*KEY_DIM + VALUE_DIM

// workspace float offsets
#define WS_CONVOUT 0                 // 8192
#define WS_ZSILU   8192              // 4096 (silu(z))
#define WS_B       12288             // 32
#define WS_A       12320             // 32
#define WS_Y       12352             // 4096 (core*norm_w)
#define WS_VARP    16448             // 128 (4 per head)
#define WS_FLAGS   16576             // 4 uints: [ticket, cnt_qkv, cnt_z, cnt_recur]

// d_out float offsets
#define OUT_HIDDEN 0                 // 2048
#define OUT_CONV   2048              // 32768
#define OUT_REC    (2048 + 32768)    // 524288

// ticket-ordered roles (producers strictly before their consumers)
#define N_QKV   2064                 // qkv (2048) + b/a (16) blocks
#define T_RECUR N_QKV                // 2064: 128 recur blocks (wait qkv)
#define N_RECUR 128
#define T_Z     (T_RECUR + N_RECUR)  // 2192: 1024 z-GEMV blocks (no deps)
#define N_Z     1024
#define T_OUT   (T_Z + N_Z)          // 3216: 512 out_proj blocks (wait recur+z)
#define N_OUT   512
#define N_BLOCKS (T_OUT + N_OUT)     // 3728

__device__ __forceinline__ float wave_reduce_sum(float v) {
    #pragma unroll
    for (int off = 32; off > 0; off >>= 1)
        v += __shfl_down(v, off, 64);
    return v;
}

__device__ __forceinline__ float silu_f(float x) { return x / (1.f + expf(-x)); }

// producer: make this block's global writes visible, then bump counter
__device__ __forceinline__ void role_done(unsigned* cnt) {
    __syncthreads();                  // drains vmcnt for all block stores
    __threadfence();                  // device-scope release (L2 writeback)
    if (threadIdx.x == 0) atomicAdd(cnt, 1u);
}

// consumer: spin until counter reaches target, then acquire
__device__ __forceinline__ void wait_cnt(unsigned* cnt, unsigned target) {
    if (threadIdx.x == 0) {
        while (__hip_atomic_load(cnt, __ATOMIC_RELAXED, __HIP_MEMORY_SCOPE_AGENT) < target)
            __builtin_amdgcn_s_sleep(2);
    }
    __syncthreads();
    __threadfence();                  // acquire side: invalidate stale cache
}

__global__ __launch_bounds__(256) void fused_kernel(
    const float* __restrict__ x,          // 2048
    const float* __restrict__ conv_state, // 8192x4
    const float* __restrict__ rec_state,  // 32x128x128
    const float* __restrict__ conv_w,     // 8192x4
    const float* __restrict__ qkv_w,      // 8192x2048
    const float* __restrict__ z_w,        // 4096x2048
    const float* __restrict__ b_w,        // 32x2048
    const float* __restrict__ a_w,        // 32x2048
    const float* __restrict__ out_w,      // 2048x4096
    const float* __restrict__ dt_bias,    // 32
    const float* __restrict__ A_log,      // 32
    const float* __restrict__ norm_w,     // 128
    float* __restrict__ ws,
    float* __restrict__ d_out)
{
    __shared__ float smem[VALUE_DIM + 64];      // reused per role
    __shared__ unsigned sticket;
    unsigned* flags = (unsigned*)(ws + WS_FLAGS);
    const int t    = threadIdx.x;
    const int lane = t & 63;
    const int wave = t >> 6;

    if (t == 0) sticket = atomicAdd(&flags[0], 1u);
    __syncthreads();
    const unsigned ticket = sticket;

    if (ticket < N_QKV) {
        // ---------- qkv / b / a GEMV rows + conv epilogue ----------
        int row = ticket * 4 + wave;            // 0..8255
        const float* w;
        if      (row < CONV_DIM)      w = qkv_w + (size_t)row * H;
        else if (row < CONV_DIM + NV) w = b_w + (size_t)(row - CONV_DIM) * H;
        else                          w = a_w + (size_t)(row - CONV_DIM - NV) * H;

        const float4* w4 = (const float4*)w;
        const float4* x4 = (const float4*)x;
        float acc = 0.f;
        #pragma unroll
        for (int i = 0; i < H / 4 / 64; ++i) {
            float4 a4 = w4[lane + i * 64];
            float4 b4 = x4[lane + i * 64];
            acc += a4.x * b4.x + a4.y * b4.y + a4.z * b4.z + a4.w * b4.w;
        }
        acc = wave_reduce_sum(acc);

        if (lane == 0) {
            if (row < CONV_DIM) {
                float4 cs = ((const float4*)conv_state)[row];
                float4 cw = ((const float4*)conv_w)[row];
                float s = cs.y * cw.x + cs.z * cw.y + cs.w * cw.z + acc * cw.w;
                ws[WS_CONVOUT + row] = silu_f(s);
                *(float4*)(d_out + OUT_CONV + row * 4) = make_float4(cs.y, cs.z, cs.w, acc);
            } else if (row < CONV_DIM + NV) {
                ws[WS_B + (row - CONV_DIM)] = acc;
            } else {
                ws[WS_A + (row - CONV_DIM - NV)] = acc;
            }
        }
        role_done(&flags[1]);
        return;
    }

    if (ticket < T_Z) {
        // ---------- recurrent state update (4 blocks/head, 32 cols each) ----------
        wait_cnt(&flags[1], N_QKV);

        float* kk      = smem;                  // 128
        float* qq      = smem + 128;            // 128
        float* part    = smem + 256;            // 8x32
        float* delta_s = smem + 512;            // 32
        float* red     = smem + 544;            // 8

        const int b  = ticket - T_RECUR;        // 0..127
        const int h  = b >> 2;
        const int c  = b & 3;
        const int kh = h >> 1;                  // vpk = 2
        const float* conv_out = ws + WS_CONVOUT;

        float qv = 0.f, kv = 0.f;
        if (t < DK) {
            qv = conv_out[kh * DK + t];
            kv = conv_out[KEY_DIM + kh * DK + t];
        }
        float qs = wave_reduce_sum(qv * qv);
        float ks = wave_reduce_sum(kv * kv);
        if (lane == 0) { red[wave] = qs; red[4 + wave] = ks; }
        __syncthreads();
        float qscale = rsqrtf(red[0] + red[1] + 1e-6f) * 0.08838834764831845f;
        float kscale = rsqrtf(red[4] + red[5] + 1e-6f);
        if (t < DK) { qq[t] = qv * qscale; kk[t] = kv * kscale; }

        float bv = ws[WS_B + h];
        float av = ws[WS_A + h];
        float beta = 1.f / (1.f + expf(-bv));
        float spi = av + dt_bias[h];
        float sp  = (spi > 20.f) ? spi : log1pf(expf(spi));
        float gexp = expf(-expf(A_log[h]) * sp);
        __syncthreads();

        const int v32 = t & 31;
        const int kc  = t >> 5;                 // 0..7, 16 k each
        const int v   = c * 32 + v32;
        const float* rec_h = rec_state + (size_t)h * DK * DV;

        float rv[16];
        float acc = 0.f;
        #pragma unroll
        for (int i = 0; i < 16; ++i) {
            int k = kc * 16 + i;
            rv[i] = rec_h[k * DV + v];
            acc += rv[i] * kk[k];
        }
        part[kc * 32 + v32] = acc;
        __syncthreads();
        if (t < 32) {
            float s = 0.f;
            #pragma unroll
            for (int j = 0; j < 8; ++j) s += part[j * 32 + t];
            float kv_mem = s * gexp;
            float vval = conv_out[2 * KEY_DIM + h * DV + c * 32 + t];
            delta_s[t] = (vval - kv_mem) * beta;
        }
        __syncthreads();

        float dv = delta_s[v32];
        float core_acc = 0.f;
        float* rec_oh = d_out + OUT_REC + (size_t)h * DK * DV;
        #pragma unroll
        for (int i = 0; i < 16; ++i) {
            int k = kc * 16 + i;
            float rn = rv[i] * gexp + kk[k] * dv;
            rec_oh[k * DV + v] = rn;
            core_acc += rn * qq[k];
        }
        part[kc * 32 + v32] = core_acc;
        __syncthreads();
        if (t < 32) {
            float core = 0.f;
            #pragma unroll
            for (int j = 0; j < 8; ++j) core += part[j * 32 + t];
            int vg = c * 32 + t;
            ws[WS_Y + h * DV + vg] = core * norm_w[vg];
            float ss = core * core;
            #pragma unroll
            for (int off = 16; off > 0; off >>= 1) ss += __shfl_down(ss, off, 32);
            if (t == 0) ws[WS_VARP + b] = ss;
        }
        role_done(&flags[3]);
        return;
    }

    if (ticket < T_OUT) {
        // ---------- z projection (independent; streams while recur runs) ----------
        int row = (ticket - T_Z) * 4 + wave;    // 0..4095
        const float4* w4 = (const float4*)(z_w + (size_t)row * H);
        const float4* x4 = (const float4*)x;
        float acc = 0.f;
        #pragma unroll
        for (int i = 0; i < H / 4 / 64; ++i) {
            float4 a4 = w4[lane + i * 64];
            float4 b4 = x4[lane + i * 64];
            acc += a4.x * b4.x + a4.y * b4.y + a4.z * b4.z + a4.w * b4.w;
        }
        acc = wave_reduce_sum(acc);
        if (lane == 0) ws[WS_ZSILU + row] = silu_f(acc);
        role_done(&flags[2]);
        return;
    }

    // ---------- out_proj: wait recur + z, build xs, GEMV ----------
    if (t == 0) {
        while (__hip_atomic_load(&flags[3], __ATOMIC_RELAXED, __HIP_MEMORY_SCOPE_AGENT) < N_RECUR)
            __builtin_amdgcn_s_sleep(2);
        while (__hip_atomic_load(&flags[2], __ATOMIC_RELAXED, __HIP_MEMORY_SCOPE_AGENT) < N_Z)
            __builtin_amdgcn_s_sleep(2);
    }
    __syncthreads();
    __threadfence();

    float* xs   = smem;                         // 4096
    float* rstd = smem + VALUE_DIM;             // 32
    if (t < NV) {
        float s = ws[WS_VARP + t * 4 + 0] + ws[WS_VARP + t * 4 + 1]
                + ws[WS_VARP + t * 4 + 2] + ws[WS_VARP + t * 4 + 3];
        rstd[t] = rsqrtf(s * (1.f / 128.f) + 1e-6f);
    }
    __syncthreads();
    #pragma unroll
    for (int i = 0; i < 4; ++i) {
        int idx = (t + i * 256) * 4;            // 0..4092
        float4 y  = *(const float4*)(ws + WS_Y + idx);
        float4 zs = *(const float4*)(ws + WS_ZSILU + idx);
        float r = rstd[idx >> 7];
        xs[idx + 0] = y.x * r * zs.x; xs[idx + 1] = y.y * r * zs.y;
        xs[idx + 2] = y.z * r * zs.z; xs[idx + 3] = y.w * r * zs.w;
    }
    __syncthreads();

    int row = (ticket - T_OUT) * 4 + wave;      // 0..2047
    const float4* w4 = (const float4*)(out_w + (size_t)row * VALUE_DIM);
    float acc = 0.f;
    #pragma unroll
    for (int i = 0; i < VALUE_DIM / 4 / 64; ++i) {
        float4 a4 = w4[lane + i * 64];
        float4 b4 = *(const float4*)(xs + (lane + i * 64) * 4);
        acc += a4.x * b4.x + a4.y * b4.y + a4.z * b4.z + a4.w * b4.w;
    }
    acc = wave_reduce_sum(acc);
    if (lane == 0) d_out[OUT_HIDDEN + row] = acc;
}

extern "C" void kernel_launch(void* const* d_in, const int* in_sizes, int n_in,
                              void* d_out, int out_size, void* d_ws, size_t ws_size,
                              hipStream_t stream) {
    const float* hidden_in  = (const float*)d_in[0];
    const float* conv_state = (const float*)d_in[1];
    const float* rec_state  = (const float*)d_in[2];
    const float* conv_w     = (const float*)d_in[3];
    const float* qkv_w      = (const float*)d_in[4];
    const float* z_w        = (const float*)d_in[5];
    const float* b_w        = (const float*)d_in[6];
    const float* a_w        = (const float*)d_in[7];
    const float* out_proj_w = (const float*)d_in[8];
    const float* dt_bias    = (const float*)d_in[9];
    const float* A_log      = (const float*)d_in[10];
    const float* norm_w     = (const float*)d_in[11];

    float* out = (float*)d_out;
    float* ws  = (float*)d_ws;

    // zero the ticket/counter flags (captured as a graph node, runs every replay)
    hipMemsetAsync((char*)d_ws + WS_FLAGS * sizeof(float), 0, 4 * sizeof(unsigned), stream);

    fused_kernel<<<N_BLOCKS, 256, 0, stream>>>(
        hidden_in, conv_state, rec_state, conv_w, qkv_w, z_w, b_w, a_w,
        out_proj_w, dt_bias, A_log, norm_w, ws, out);
}

// Round 6
// 33.188 us; speedup vs baseline: 16.0834x; 16.0834x over previous
//
#include <hip/hip_runtime.h>
#include <math.h>

#define H 2048
#define NV 32
#define DK 128
#define DV 128
#define KEY_DIM 2048
#define VALUE_DIM 4096
#define CONV_DIM 8192               // 2*KEY_DIM + VALUE_DIM

// workspace float offsets
#define WS_CONVOUT 0                 // 8192
#define WS_ZSILU   8192              // 4096 (silu(z))
#define WS_B       12288             // 32
#define WS_A       12320             // 32
#define WS_Y       12352             // 4096 (core*norm_w)
#define WS_VARP    16448             // 128 (4 per head)

// d_out float offsets
#define OUT_HIDDEN 0                 // 2048
#define OUT_CONV   2048              // 32768
#define OUT_REC    (2048 + 32768)    // 524288

__device__ __forceinline__ float wave_reduce_sum(float v) {
    #pragma unroll
    for (int off = 32; off > 0; off >>= 1)
        v += __shfl_down(v, off, 64);
    return v;
}

__device__ __forceinline__ float silu_f(float x) { return x / (1.f + expf(-x)); }

// dual-row GEMV inner: both rows' weights preloaded (16 loads in flight),
// x read from LDS. Returns accA/accB reduced to lane 0.
__device__ __forceinline__ void gemv2(const float4* __restrict__ wA4,
                                      const float4* __restrict__ wB4,
                                      const float4* __restrict__ xs4,
                                      int lane, int n4,   // n4 = row len/4/64
                                      float& accA, float& accB) {
    float4 wa[16], wb[16];
    #pragma unroll
    for (int i = 0; i < 16; ++i) if (i < n4) wa[i] = wA4[lane + i * 64];
    #pragma unroll
    for (int i = 0; i < 16; ++i) if (i < n4) wb[i] = wB4[lane + i * 64];
    float a = 0.f, b = 0.f;
    #pragma unroll
    for (int i = 0; i < 16; ++i) {
        if (i < n4) {
            float4 xv = xs4[lane + i * 64];
            a += wa[i].x * xv.x + wa[i].y * xv.y + wa[i].z * xv.z + wa[i].w * xv.w;
            b += wb[i].x * xv.x + wb[i].y * xv.y + wb[i].z * xv.z + wb[i].w * xv.w;
        }
    }
    accA = wave_reduce_sum(a);
    accB = wave_reduce_sum(b);
}

// ---------------- Kernel 1: qkv + b + a projections, conv update ----------------
// 2 rows per wave, 8 rows per block. Rows: [0,8192) qkv, [8192,8224) b, [8224,8256) a.
__global__ __launch_bounds__(256) void proj_conv_kernel(
    const float* __restrict__ x,          // 2048
    const float* __restrict__ qkv_w,      // 8192x2048
    const float* __restrict__ b_w,        // 32x2048
    const float* __restrict__ a_w,        // 32x2048
    const float* __restrict__ conv_state, // 8192x4
    const float* __restrict__ conv_w,     // 8192x4
    float* __restrict__ ws,
    float* __restrict__ d_out)
{
    __shared__ float4 xs4[H / 4];         // 8 KB
    const int t = threadIdx.x, lane = t & 63, wave = t >> 6;
    const float4* xp = (const float4*)x;
    xs4[t] = xp[t]; xs4[t + 256] = xp[t + 256];
    __syncthreads();

    int pair = blockIdx.x * 4 + wave;     // 0..4127; segment boundaries are even
    int rowA = pair * 2;
    const float *wA, *wB;
    if (rowA < CONV_DIM) {
        wA = qkv_w + (size_t)rowA * H;
    } else if (rowA < CONV_DIM + NV) {
        wA = b_w + (size_t)(rowA - CONV_DIM) * H;
    } else {
        wA = a_w + (size_t)(rowA - CONV_DIM - NV) * H;
    }
    wB = wA + H;

    float accA, accB;
    gemv2((const float4*)wA, (const float4*)wB, xs4, lane, H / 4 / 64, accA, accB);

    if (lane == 0) {
        #pragma unroll
        for (int r = 0; r < 2; ++r) {
            int row = rowA + r;
            float acc = r ? accB : accA;
            if (row < CONV_DIM) {
                float4 cs = ((const float4*)conv_state)[row];
                float4 cw = ((const float4*)conv_w)[row];
                float s = cs.y * cw.x + cs.z * cw.y + cs.w * cw.z + acc * cw.w;
                ws[WS_CONVOUT + row] = silu_f(s);
                *(float4*)(d_out + OUT_CONV + row * 4) = make_float4(cs.y, cs.z, cs.w, acc);
            } else if (row < CONV_DIM + NV) {
                ws[WS_B + (row - CONV_DIM)] = acc;
            } else {
                ws[WS_A + (row - CONV_DIM - NV)] = acc;
            }
        }
    }
}

// ---------------- Kernel 2: recur (blocks 0..127) || z GEMV (blocks 128..639) ----
__global__ __launch_bounds__(256) void mid_kernel(
    const float* __restrict__ x,          // 2048
    const float* __restrict__ z_w,        // 4096x2048
    const float* __restrict__ rec_state,  // 32x128x128
    float* __restrict__ ws,
    const float* __restrict__ dt_bias,    // 32
    const float* __restrict__ A_log,      // 32
    const float* __restrict__ norm_w,     // 128
    float* __restrict__ d_out)
{
    __shared__ float smem[H];             // 8 KB, role-dependent use
    const int t = threadIdx.x, lane = t & 63, wave = t >> 6;

    if (blockIdx.x >= 128) {
        // ---- z projection: 2 rows per wave ----
        float4* xs4 = (float4*)smem;
        const float4* xp = (const float4*)x;
        xs4[t] = xp[t]; xs4[t + 256] = xp[t + 256];
        __syncthreads();
        int pair = (blockIdx.x - 128) * 4 + wave;  // 0..2047
        int rowA = pair * 2;
        const float4* wA = (const float4*)(z_w + (size_t)rowA * H);
        float accA, accB;
        gemv2(wA, wA + H / 4, xs4, lane, H / 4 / 64, accA, accB);
        if (lane == 0) {
            ws[WS_ZSILU + rowA]     = silu_f(accA);
            ws[WS_ZSILU + rowA + 1] = silu_f(accB);
        }
        return;
    }

    // ---- recurrent state update: 4 blocks/head, 32 cols each ----
    float* kk      = smem;                // 128
    float* qq      = smem + 128;          // 128
    float* part    = smem + 256;          // 8x32
    float* delta_s = smem + 512;          // 32
    float* red     = smem + 544;          // 8

    const int b  = blockIdx.x;
    const int h  = b >> 2;
    const int c  = b & 3;
    const int kh = h >> 1;                // vpk = 2
    const float* conv_out = ws + WS_CONVOUT;

    float qv = 0.f, kv = 0.f;
    if (t < DK) {
        qv = conv_out[kh * DK + t];
        kv = conv_out[KEY_DIM + kh * DK + t];
    }
    float qs = wave_reduce_sum(qv * qv);
    float ks = wave_reduce_sum(kv * kv);
    if (lane == 0) { red[wave] = qs; red[4 + wave] = ks; }
    __syncthreads();
    float qscale = rsqrtf(red[0] + red[1] + 1e-6f) * 0.08838834764831845f; // *1/sqrt(128)
    float kscale = rsqrtf(red[4] + red[5] + 1e-6f);
    if (t < DK) { qq[t] = qv * qscale; kk[t] = kv * kscale; }

    float bv = ws[WS_B + h];
    float av = ws[WS_A + h];
    float beta = 1.f / (1.f + expf(-bv));
    float spi = av + dt_bias[h];
    float sp  = (spi > 20.f) ? spi : log1pf(expf(spi));
    float gexp = expf(-expf(A_log[h]) * sp);
    __syncthreads();

    const int v32 = t & 31;
    const int kc  = t >> 5;               // 0..7, 16 k each
    const int v   = c * 32 + v32;
    const float* rec_h = rec_state + (size_t)h * DK * DV;

    float rv[16];
    float acc = 0.f;
    #pragma unroll
    for (int i = 0; i < 16; ++i) {
        int k = kc * 16 + i;
        rv[i] = rec_h[k * DV + v];
        acc += rv[i] * kk[k];
    }
    part[kc * 32 + v32] = acc;
    __syncthreads();
    if (t < 32) {
        float s = 0.f;
        #pragma unroll
        for (int j = 0; j < 8; ++j) s += part[j * 32 + t];
        float kv_mem = s * gexp;
        float vval = conv_out[2 * KEY_DIM + h * DV + c * 32 + t];
        delta_s[t] = (vval - kv_mem) * beta;
    }
    __syncthreads();

    float dv = delta_s[v32];
    float core_acc = 0.f;
    float* rec_oh = d_out + OUT_REC + (size_t)h * DK * DV;
    #pragma unroll
    for (int i = 0; i < 16; ++i) {
        int k = kc * 16 + i;
        float rn = rv[i] * gexp + kk[k] * dv;
        rec_oh[k * DV + v] = rn;
        core_acc += rn * qq[k];
    }
    part[kc * 32 + v32] = core_acc;
    __syncthreads();
    if (t < 32) {
        float core = 0.f;
        #pragma unroll
        for (int j = 0; j < 8; ++j) core += part[j * 32 + t];
        int vg = c * 32 + t;
        ws[WS_Y + h * DV + vg] = core * norm_w[vg];
        float ss = core * core;
        #pragma unroll
        for (int off = 16; off > 0; off >>= 1) ss += __shfl_down(ss, off, 32);
        if (t == 0) ws[WS_VARP + b] = ss;
    }
}

// ---------------- Kernel 3: norm+zsilu finish, out_proj GEMV (2048x4096) -----
// 2 rows per wave, 8 rows per block, 256 blocks.
__global__ __launch_bounds__(256) void outproj_kernel(
    const float* __restrict__ w,        // 2048x4096
    const float* __restrict__ ws,
    float* __restrict__ d_out)
{
    __shared__ float xs[VALUE_DIM];     // 16 KB
    __shared__ float rstd[NV];
    const int t = threadIdx.x, lane = t & 63, wave = t >> 6;

    if (t < NV) {
        float s = ws[WS_VARP + t * 4 + 0] + ws[WS_VARP + t * 4 + 1]
                + ws[WS_VARP + t * 4 + 2] + ws[WS_VARP + t * 4 + 3];
        rstd[t] = rsqrtf(s * (1.f / 128.f) + 1e-6f);
    }
    __syncthreads();
    #pragma unroll
    for (int i = 0; i < 4; ++i) {
        int idx = (t + i * 256) * 4;    // 0..4092
        float4 y  = *(const float4*)(ws + WS_Y + idx);
        float4 zs = *(const float4*)(ws + WS_ZSILU + idx);
        float r = rstd[idx >> 7];
        xs[idx + 0] = y.x * r * zs.x; xs[idx + 1] = y.y * r * zs.y;
        xs[idx + 2] = y.z * r * zs.z; xs[idx + 3] = y.w * r * zs.w;
    }
    __syncthreads();

    int pair = blockIdx.x * 4 + wave;   // 0..1023
    int rowA = pair * 2;
    const float4* wA = (const float4*)(w + (size_t)rowA * VALUE_DIM);
    float accA, accB;
    gemv2(wA, wA + VALUE_DIM / 4, (const float4*)xs, lane, VALUE_DIM / 4 / 64, accA, accB);
    if (lane == 0) {
        d_out[OUT_HIDDEN + rowA]     = accA;
        d_out[OUT_HIDDEN + rowA + 1] = accB;
    }
}

extern "C" void kernel_launch(void* const* d_in, const int* in_sizes, int n_in,
                              void* d_out, int out_size, void* d_ws, size_t ws_size,
                              hipStream_t stream) {
    const float* hidden_in  = (const float*)d_in[0];
    const float* conv_state = (const float*)d_in[1];
    const float* rec_state  = (const float*)d_in[2];
    const float* conv_w     = (const float*)d_in[3];
    const float* qkv_w      = (const float*)d_in[4];
    const float* z_w        = (const float*)d_in[5];
    const float* b_w        = (const float*)d_in[6];
    const float* a_w        = (const float*)d_in[7];
    const float* out_proj_w = (const float*)d_in[8];
    const float* dt_bias    = (const float*)d_in[9];
    const float* A_log      = (const float*)d_in[10];
    const float* norm_w     = (const float*)d_in[11];

    float* out = (float*)d_out;
    float* ws  = (float*)d_ws;

    proj_conv_kernel<<<(CONV_DIM + 2 * NV) / 8, 256, 0, stream>>>(
        hidden_in, qkv_w, b_w, a_w, conv_state, conv_w, ws, out);
    mid_kernel<<<128 + VALUE_DIM / 8, 256, 0, stream>>>(
        hidden_in, z_w, rec_state, ws, dt_bias, A_log, norm_w, out);
    outproj_kernel<<<H / 8, 256, 0, stream>>>(out_proj_w, ws, out);
}

// Round 8
// 32.021 us; speedup vs baseline: 16.6695x; 1.0364x over previous
//
#include <hip/hip_runtime.h>
#include <math.h>

#define H 2048
#define NV 32
#define DK 128
#define DV 128
#define KEY_DIM 2048
#define VALUE_DIM 4096
#define CONV_DIM 8192               // 2*KEY_DIM + VALUE_DIM

// workspace float offsets
#define WS_CONVOUT 0                 // 8192
#define WS_ZSILU   8192              // 4096 (silu(z))
#define WS_B       12288             // 32
#define WS_A       12320             // 32
#define WS_Y       12352             // 4096 (core*norm_w)
#define WS_VARP    16448             // 128 (4 per head)

// d_out float offsets
#define OUT_HIDDEN 0                 // 2048
#define OUT_CONV   2048              // 32768
#define OUT_REC    (2048 + 32768)    // 524288

typedef float floatx4 __attribute__((ext_vector_type(4)));

__device__ __forceinline__ float wave_reduce_sum(float v) {
    #pragma unroll
    for (int off = 32; off > 0; off >>= 1)
        v += __shfl_down(v, off, 64);
    return v;
}

__device__ __forceinline__ float silu_f(float x) { return x / (1.f + expf(-x)); }

// non-temporal float4 load/store (single-use streaming data; nt flag on gfx950)
__device__ __forceinline__ float4 ntload4(const float4* p) {
    floatx4 r = __builtin_nontemporal_load((const floatx4*)p);
    return make_float4(r.x, r.y, r.z, r.w);
}
__device__ __forceinline__ float ntloadf(const float* p) {
    return __builtin_nontemporal_load(p);
}
__device__ __forceinline__ void ntstoref(float* p, float v) {
    __builtin_nontemporal_store(v, p);
}
__device__ __forceinline__ void ntstore4(float4* p, float4 v) {
    floatx4 r; r.x = v.x; r.y = v.y; r.z = v.z; r.w = v.w;
    __builtin_nontemporal_store(r, (floatx4*)p);
}

// ---------------- Kernel 1: qkv + b + a projections, conv update ----------------
// One wave per row. Rows: [0,8192) qkv, [8192,8224) b, [8224,8256) a.
__global__ __launch_bounds__(256) void proj_conv_kernel(
    const float* __restrict__ x,          // 2048
    const float* __restrict__ qkv_w,      // 8192x2048
    const float* __restrict__ b_w,        // 32x2048
    const float* __restrict__ a_w,        // 32x2048
    const float* __restrict__ conv_state, // 8192x4
    const float* __restrict__ conv_w,     // 8192x4
    float* __restrict__ ws,
    float* __restrict__ d_out)
{
    int row  = blockIdx.x * 4 + (threadIdx.x >> 6);
    int lane = threadIdx.x & 63;

    const float* w;
    if      (row < CONV_DIM)        w = qkv_w + (size_t)row * H;
    else if (row < CONV_DIM + NV)   w = b_w + (size_t)(row - CONV_DIM) * H;
    else                            w = a_w + (size_t)(row - CONV_DIM - NV) * H;

    const float4* w4 = (const float4*)w;
    const float4* x4 = (const float4*)x;
    float acc = 0.f;
    #pragma unroll
    for (int i = 0; i < H / 4 / 64; ++i) {   // 8 iterations, 16B/lane
        float4 a4 = ntload4(&w4[lane + i * 64]);
        float4 b4 = x4[lane + i * 64];
        acc += a4.x * b4.x + a4.y * b4.y + a4.z * b4.z + a4.w * b4.w;
    }
    acc = wave_reduce_sum(acc);

    if (lane == 0) {
        if (row < CONV_DIM) {
            float4 cs = ntload4(&((const float4*)conv_state)[row]);
            float4 cw = ntload4(&((const float4*)conv_w)[row]);
            float s = cs.y * cw.x + cs.z * cw.y + cs.w * cw.z + acc * cw.w;
            ws[WS_CONVOUT + row] = silu_f(s);
            ntstore4((float4*)(d_out + OUT_CONV + row * 4),
                     make_float4(cs.y, cs.z, cs.w, acc));
        } else if (row < CONV_DIM + NV) {
            ws[WS_B + (row - CONV_DIM)] = acc;
        } else {
            ws[WS_A + (row - CONV_DIM - NV)] = acc;
        }
    }
}

// ---------------- Kernel 2: recur (blocks 0..127) || z GEMV (blocks 128..1151) ----
__global__ __launch_bounds__(256) void mid_kernel(
    const float* __restrict__ x,          // 2048
    const float* __restrict__ z_w,        // 4096x2048
    const float* __restrict__ rec_state,  // 32x128x128
    float* __restrict__ ws,
    const float* __restrict__ dt_bias,    // 32
    const float* __restrict__ A_log,      // 32
    const float* __restrict__ norm_w,     // 128
    float* __restrict__ d_out)
{
    const int t = threadIdx.x;

    if (blockIdx.x >= 128) {
        // ---- z projection: one wave per row ----
        int row  = (blockIdx.x - 128) * 4 + (t >> 6);  // 0..4095
        int lane = t & 63;
        const float4* w4 = (const float4*)(z_w + (size_t)row * H);
        const float4* x4 = (const float4*)x;
        float acc = 0.f;
        #pragma unroll
        for (int i = 0; i < H / 4 / 64; ++i) {
            float4 a4 = ntload4(&w4[lane + i * 64]);
            float4 b4 = x4[lane + i * 64];
            acc += a4.x * b4.x + a4.y * b4.y + a4.z * b4.z + a4.w * b4.w;
        }
        acc = wave_reduce_sum(acc);
        if (lane == 0) ws[WS_ZSILU + row] = silu_f(acc);
        return;
    }

    // ---- recurrent state update: 4 blocks/head, 32 cols each ----
    __shared__ float kk[DK], qq[DK];
    __shared__ float part[8][32];
    __shared__ float delta_s[32];
    __shared__ float red[8];

    const int b    = blockIdx.x;
    const int h    = b >> 2;
    const int c    = b & 3;
    const int lane = t & 63;
    const int wave = t >> 6;
    const int kh   = h >> 1;            // vpk = 2

    const float* conv_out = ws + WS_CONVOUT;

    float qv = 0.f, kv = 0.f;
    if (t < DK) {
        qv = conv_out[kh * DK + t];
        kv = conv_out[KEY_DIM + kh * DK + t];
    }
    float qs = wave_reduce_sum(qv * qv);
    float ks = wave_reduce_sum(kv * kv);
    if (lane == 0) { red[wave] = qs; red[4 + wave] = ks; }
    __syncthreads();
    float qscale = rsqrtf(red[0] + red[1] + 1e-6f) * 0.08838834764831845f; // *1/sqrt(128)
    float kscale = rsqrtf(red[4] + red[5] + 1e-6f);
    if (t < DK) { qq[t] = qv * qscale; kk[t] = kv * kscale; }

    float bv = ws[WS_B + h];
    float av = ws[WS_A + h];
    float beta = 1.f / (1.f + expf(-bv));
    float spi = av + dt_bias[h];
    float sp  = (spi > 20.f) ? spi : log1pf(expf(spi));
    float gexp = expf(-expf(A_log[h]) * sp);
    __syncthreads();

    const int v32 = t & 31;
    const int kc  = t >> 5;             // 0..7, 16 k each
    const int v   = c * 32 + v32;
    const float* rec_h = rec_state + (size_t)h * DK * DV;

    // pass 1: partial kv_mem; rec values stay in registers
    float rv[16];
    float acc = 0.f;
    #pragma unroll
    for (int i = 0; i < 16; ++i) {
        int k = kc * 16 + i;
        rv[i] = ntloadf(&rec_h[k * DV + v]);
        acc += rv[i] * kk[k];
    }
    part[kc][v32] = acc;
    __syncthreads();
    if (t < 32) {
        float s = 0.f;
        #pragma unroll
        for (int j = 0; j < 8; ++j) s += part[j][t];
        float kv_mem = s * gexp;
        float vval = conv_out[2 * KEY_DIM + h * DV + c * 32 + t];
        delta_s[t] = (vval - kv_mem) * beta;
    }
    __syncthreads();

    // pass 2: rec_new = gexp*rec + kk ⊗ delta; core partial
    float dv = delta_s[v32];
    float core_acc = 0.f;
    float* rec_oh = d_out + OUT_REC + (size_t)h * DK * DV;
    #pragma unroll
    for (int i = 0; i < 16; ++i) {
        int k = kc * 16 + i;
        float rn = rv[i] * gexp + kk[k] * dv;
        ntstoref(&rec_oh[k * DV + v], rn);
        core_acc += rn * qq[k];
    }
    part[kc][v32] = core_acc;
    __syncthreads();
    if (t < 32) {
        float core = 0.f;
        #pragma unroll
        for (int j = 0; j < 8; ++j) core += part[j][t];
        int vg = c * 32 + t;
        ws[WS_Y + h * DV + vg] = core * norm_w[vg];
        float ss = core * core;
        #pragma unroll
        for (int off = 16; off > 0; off >>= 1) ss += __shfl_down(ss, off, 32);
        if (t == 0) ws[WS_VARP + b] = ss;
    }
}

// ---------------- Kernel 3: norm+zsilu finish, out_proj GEMV (2048 x 4096) -----
__global__ __launch_bounds__(256) void outproj_kernel(
    const float* __restrict__ w,        // 2048x4096
    const float* __restrict__ ws,
    float* __restrict__ d_out)
{
    __shared__ float xs[VALUE_DIM];     // 16 KB
    __shared__ float rstd[NV];
    const int t = threadIdx.x;

    if (t < NV) {
        float s = ws[WS_VARP + t * 4 + 0] + ws[WS_VARP + t * 4 + 1]
                + ws[WS_VARP + t * 4 + 2] + ws[WS_VARP + t * 4 + 3];
        rstd[t] = rsqrtf(s * (1.f / 128.f) + 1e-6f);
    }
    __syncthreads();
    #pragma unroll
    for (int i = 0; i < 4; ++i) {
        int idx = (t + i * 256) * 4;    // 0..4092
        float4 y  = *(const float4*)(ws + WS_Y + idx);
        float4 zs = *(const float4*)(ws + WS_ZSILU + idx);
        float r = rstd[idx >> 7];
        xs[idx + 0] = y.x * r * zs.x; xs[idx + 1] = y.y * r * zs.y;
        xs[idx + 2] = y.z * r * zs.z; xs[idx + 3] = y.w * r * zs.w;
    }
    __syncthreads();

    int row  = blockIdx.x * 4 + (t >> 6);
    int lane = t & 63;
    const float4* w4 = (const float4*)(w + (size_t)row * VALUE_DIM);
    float acc = 0.f;
    #pragma unroll
    for (int i = 0; i < VALUE_DIM / 4 / 64; ++i) {  // 16 iterations
        float4 a4 = ntload4(&w4[lane + i * 64]);
        float4 b4 = *(const float4*)(xs + (lane + i * 64) * 4);
        acc += a4.x * b4.x + a4.y * b4.y + a4.z * b4.z + a4.w * b4.w;
    }
    acc = wave_reduce_sum(acc);
    if (lane == 0) ntstoref(&d_out[OUT_HIDDEN + row], acc);
}

extern "C" void kernel_launch(void* const* d_in, const int* in_sizes, int n_in,
                              void* d_out, int out_size, void* d_ws, size_t ws_size,
                              hipStream_t stream) {
    const float* hidden_in  = (const float*)d_in[0];
    const float* conv_state = (const float*)d_in[1];
    const float* rec_state  = (const float*)d_in[2];
    const float* conv_w     = (const float*)d_in[3];
    const float* qkv_w      = (const float*)d_in[4];
    const float* z_w        = (const float*)d_in[5];
    const float* b_w        = (const float*)d_in[6];
    const float* a_w        = (const float*)d_in[7];
    const float* out_proj_w = (const float*)d_in[8];
    const float* dt_bias    = (const float*)d_in[9];
    const float* A_log      = (const float*)d_in[10];
    const float* norm_w     = (const float*)d_in[11];

    float* out = (float*)d_out;
    float* ws  = (float*)d_ws;

    proj_conv_kernel<<<(CONV_DIM + 2 * NV) / 4, 256, 0, stream>>>(
        hidden_in, qkv_w, b_w, a_w, conv_state, conv_w, ws, out);
    mid_kernel<<<128 + VALUE_DIM / 4, 256, 0, stream>>>(
        hidden_in, z_w, rec_state, ws, dt_bias, A_log, norm_w, out);
    outproj_kernel<<<H / 4, 256, 0, stream>>>(out_proj_w, ws, out);
}

// Round 9
// 30.401 us; speedup vs baseline: 17.5574x; 1.0533x over previous
//
#include <hip/hip_runtime.h>
#include <math.h>

#define H 2048
#define NV 32
#define DK 128
#define DV 128
#define KEY_DIM 2048
#define VALUE_DIM 4096
#define CONV_DIM 8192               // 2*KEY_DIM + VALUE_DIM

// workspace float offsets
#define WS_CONVOUT 0                 // 8192
#define WS_ZSILU   8192              // 4096 (silu(z))
#define WS_B       12288             // 32
#define WS_A       12320             // 32
#define WS_Y       12352             // 4096 (core*norm_w)
#define WS_VARP    16448             // 128 (4 per head)

// d_out float offsets
#define OUT_HIDDEN 0                 // 2048
#define OUT_CONV   2048              // 32768
#define OUT_REC    (2048 + 32768)    // 524288

__device__ __forceinline__ float wave_reduce_sum(float v) {
    #pragma unroll
    for (int off = 32; off > 0; off >>= 1)
        v += __shfl_down(v, off, 64);
    return v;
}

__device__ __forceinline__ float silu_f(float x) { return x / (1.f + expf(-x)); }

// one-row GEMV dot: row weights vs x, wave-reduced to lane 0
__device__ __forceinline__ float gemv_row(const float* __restrict__ w,
                                          const float4* __restrict__ x4,
                                          int lane, int n4) {
    const float4* w4 = (const float4*)w;
    float acc = 0.f;
    #pragma unroll 16
    for (int i = 0; i < n4; ++i) {
        float4 a4 = w4[lane + i * 64];
        float4 b4 = x4[lane + i * 64];
        acc += a4.x * b4.x + a4.y * b4.y + a4.z * b4.z + a4.w * b4.w;
    }
    return wave_reduce_sum(acc);
}

// ---------------- Kernel 1: qkv + b + a projections, conv update ----------------
// 2048 blocks (8/CU exact). Wave w owns qkv row w; waves 0..63 also do b/a rows.
__global__ __launch_bounds__(256) void proj_conv_kernel(
    const float* __restrict__ x,          // 2048
    const float* __restrict__ qkv_w,      // 8192x2048
    const float* __restrict__ b_w,        // 32x2048
    const float* __restrict__ a_w,        // 32x2048
    const float* __restrict__ conv_state, // 8192x4
    const float* __restrict__ conv_w,     // 8192x4
    float* __restrict__ ws,
    float* __restrict__ d_out)
{
    const int w    = blockIdx.x * 4 + (threadIdx.x >> 6);  // wave id 0..8191
    const int lane = threadIdx.x & 63;
    const float4* x4 = (const float4*)x;

    // primary: qkv row w
    float acc = gemv_row(qkv_w + (size_t)w * H, x4, lane, H / 4 / 64);
    if (lane == 0) {
        float4 cs = ((const float4*)conv_state)[w];
        float4 cw = ((const float4*)conv_w)[w];
        float s = cs.y * cw.x + cs.z * cw.y + cs.w * cw.z + acc * cw.w;
        ws[WS_CONVOUT + w] = silu_f(s);
        *(float4*)(d_out + OUT_CONV + w * 4) = make_float4(cs.y, cs.z, cs.w, acc);
    }

    // extra: b/a rows on waves 0..63
    if (w < 2 * NV) {
        const float* wp = (w < NV) ? b_w + (size_t)w * H
                                   : a_w + (size_t)(w - NV) * H;
        float acc2 = gemv_row(wp, x4, lane, H / 4 / 64);
        if (lane == 0) {
            if (w < NV) ws[WS_B + w] = acc2;
            else        ws[WS_A + (w - NV)] = acc2;
        }
    }
}

// ---------------- Kernel 2: recur (blocks 0..127) || z GEMV (blocks 128..1023) ----
// 1024 blocks (4/CU exact). Recur blocks have lowest IDs -> start first, hide
// under the z weight stream.
__global__ __launch_bounds__(256) void mid_kernel(
    const float* __restrict__ x,          // 2048
    const float* __restrict__ z_w,        // 4096x2048
    const float* __restrict__ rec_state,  // 32x128x128
    float* __restrict__ ws,
    const float* __restrict__ dt_bias,    // 32
    const float* __restrict__ A_log,      // 32
    const float* __restrict__ norm_w,     // 128
    float* __restrict__ d_out)
{
    const int t = threadIdx.x;

    if (blockIdx.x >= 128) {
        // ---- z projection: wave zw owns row zw; waves 0..511 take a 2nd row ----
        const int zw   = (blockIdx.x - 128) * 4 + (t >> 6);  // 0..3583
        const int lane = t & 63;
        const float4* x4 = (const float4*)x;
        float acc = gemv_row(z_w + (size_t)zw * H, x4, lane, H / 4 / 64);
        if (lane == 0) ws[WS_ZSILU + zw] = silu_f(acc);
        if (zw < VALUE_DIM - 3584) {                          // 512 extra rows
            int row2 = 3584 + zw;
            float acc2 = gemv_row(z_w + (size_t)row2 * H, x4, lane, H / 4 / 64);
            if (lane == 0) ws[WS_ZSILU + row2] = silu_f(acc2);
        }
        return;
    }

    // ---- recurrent state update: 4 blocks/head, 32 cols each ----
    __shared__ float kk[DK], qq[DK];
    __shared__ float part[8][32];
    __shared__ float delta_s[32];
    __shared__ float red[8];

    const int b    = blockIdx.x;
    const int h    = b >> 2;
    const int c    = b & 3;
    const int lane = t & 63;
    const int wave = t >> 6;
    const int kh   = h >> 1;            // vpk = 2

    const float* conv_out = ws + WS_CONVOUT;

    float qv = 0.f, kv = 0.f;
    if (t < DK) {
        qv = conv_out[kh * DK + t];
        kv = conv_out[KEY_DIM + kh * DK + t];
    }
    float qs = wave_reduce_sum(qv * qv);
    float ks = wave_reduce_sum(kv * kv);
    if (lane == 0) { red[wave] = qs; red[4 + wave] = ks; }
    __syncthreads();
    float qscale = rsqrtf(red[0] + red[1] + 1e-6f) * 0.08838834764831845f; // *1/sqrt(128)
    float kscale = rsqrtf(red[4] + red[5] + 1e-6f);
    if (t < DK) { qq[t] = qv * qscale; kk[t] = kv * kscale; }

    float bv = ws[WS_B + h];
    float av = ws[WS_A + h];
    float beta = 1.f / (1.f + expf(-bv));
    float spi = av + dt_bias[h];
    float sp  = (spi > 20.f) ? spi : log1pf(expf(spi));
    float gexp = expf(-expf(A_log[h]) * sp);
    __syncthreads();

    const int v32 = t & 31;
    const int kc  = t >> 5;             // 0..7, 16 k each
    const int v   = c * 32 + v32;
    const float* rec_h = rec_state + (size_t)h * DK * DV;

    // pass 1: partial kv_mem; rec values stay in registers
    float rv[16];
    float acc = 0.f;
    #pragma unroll
    for (int i = 0; i < 16; ++i) {
        int k = kc * 16 + i;
        rv[i] = rec_h[k * DV + v];
        acc += rv[i] * kk[k];
    }
    part[kc][v32] = acc;
    __syncthreads();
    if (t < 32) {
        float s = 0.f;
        #pragma unroll
        for (int j = 0; j < 8; ++j) s += part[j][t];
        float kv_mem = s * gexp;
        float vval = conv_out[2 * KEY_DIM + h * DV + c * 32 + t];
        delta_s[t] = (vval - kv_mem) * beta;
    }
    __syncthreads();

    // pass 2: rec_new = gexp*rec + kk ⊗ delta; core partial
    float dv = delta_s[v32];
    float core_acc = 0.f;
    float* rec_oh = d_out + OUT_REC + (size_t)h * DK * DV;
    #pragma unroll
    for (int i = 0; i < 16; ++i) {
        int k = kc * 16 + i;
        float rn = rv[i] * gexp + kk[k] * dv;
        rec_oh[k * DV + v] = rn;
        core_acc += rn * qq[k];
    }
    part[kc][v32] = core_acc;
    __syncthreads();
    if (t < 32) {
        float core = 0.f;
        #pragma unroll
        for (int j = 0; j < 8; ++j) core += part[j][t];
        int vg = c * 32 + t;
        ws[WS_Y + h * DV + vg] = core * norm_w[vg];
        float ss = core * core;
        #pragma unroll
        for (int off = 16; off > 0; off >>= 1) ss += __shfl_down(ss, off, 32);
        if (t == 0) ws[WS_VARP + b] = ss;
    }
}

// ---------------- Kernel 3: norm+zsilu finish, out_proj GEMV (2048 x 4096) -----
__global__ __launch_bounds__(256) void outproj_kernel(
    const float* __restrict__ w,        // 2048x4096
    const float* __restrict__ ws,
    float* __restrict__ d_out)
{
    __shared__ float xs[VALUE_DIM];     // 16 KB
    __shared__ float rstd[NV];
    const int t = threadIdx.x;

    if (t < NV) {
        float s = ws[WS_VARP + t * 4 + 0] + ws[WS_VARP + t * 4 + 1]
                + ws[WS_VARP + t * 4 + 2] + ws[WS_VARP + t * 4 + 3];
        rstd[t] = rsqrtf(s * (1.f / 128.f) + 1e-6f);
    }
    __syncthreads();
    #pragma unroll
    for (int i = 0; i < 4; ++i) {
        int idx = (t + i * 256) * 4;    // 0..4092
        float4 y  = *(const float4*)(ws + WS_Y + idx);
        float4 zs = *(const float4*)(ws + WS_ZSILU + idx);
        float r = rstd[idx >> 7];
        xs[idx + 0] = y.x * r * zs.x; xs[idx + 1] = y.y * r * zs.y;
        xs[idx + 2] = y.z * r * zs.z; xs[idx + 3] = y.w * r * zs.w;
    }
    __syncthreads();

    int row  = blockIdx.x * 4 + (t >> 6);
    int lane = t & 63;
    const float4* w4 = (const float4*)(w + (size_t)row * VALUE_DIM);
    float acc = 0.f;
    #pragma unroll
    for (int i = 0; i < VALUE_DIM / 4 / 64; ++i) {  // 16 iterations
        float4 a4 = w4[lane + i * 64];
        float4 b4 = *(const float4*)(xs + (lane + i * 64) * 4);
        acc += a4.x * b4.x + a4.y * b4.y + a4.z * b4.z + a4.w * b4.w;
    }
    acc = wave_reduce_sum(acc);
    if (lane == 0) d_out[OUT_HIDDEN + row] = acc;
}

extern "C" void kernel_launch(void* const* d_in, const int* in_sizes, int n_in,
                              void* d_out, int out_size, void* d_ws, size_t ws_size,
                              hipStream_t stream) {
    const float* hidden_in  = (const float*)d_in[0];
    const float* conv_state = (const float*)d_in[1];
    const float* rec_state  = (const float*)d_in[2];
    const float* conv_w     = (const float*)d_in[3];
    const float* qkv_w      = (const float*)d_in[4];
    const float* z_w        = (const float*)d_in[5];
    const float* b_w        = (const float*)d_in[6];
    const float* a_w        = (const float*)d_in[7];
    const float* out_proj_w = (const float*)d_in[8];
    const float* dt_bias    = (const float*)d_in[9];
    const float* A_log      = (const float*)d_in[10];
    const float* norm_w     = (const float*)d_in[11];

    float* out = (float*)d_out;
    float* ws  = (float*)d_ws;

    proj_conv_kernel<<<2048, 256, 0, stream>>>(
        hidden_in, qkv_w, b_w, a_w, conv_state, conv_w, ws, out);
    mid_kernel<<<1024, 256, 0, stream>>>(
        hidden_in, z_w, rec_state, ws, dt_bias, A_log, norm_w, out);
    outproj_kernel<<<H / 4, 256, 0, stream>>>(out_proj_w, ws, out);
}